// Round 5
// baseline (236.713 us; speedup 1.0000x reference)
//
#include <hip/hip_runtime.h>
#include <hip/hip_bf16.h>

// GAT layer for MI355X (gfx950). FP32 in/out.
//   K1 gat_wh   : Wh = h @ W^T via split-bf16 MFMA -> WhT_hi/lo[128][8192] bf16.
//   K2 gat_f12  : f1/f2 logits (fp32, pre-scaled by log2e).
//   K3 gat_flash: barrier-free per-wave flash softmax+PV with ISSUE-ORDER
//                 pipelining: per k-step issue B(t+1)/f2(t+1) FIRST, adj(t+2)
//                 LAST, compute with regs of step t. In-order vmcnt then gives
//                 every adj (HBM) load a 2-step latency budget and the queue
//                 never drains. R4 post-mortem: adj issued first + f2/B used
//                 same-step forced a full HBM drain every step (0.66 TB/s).

typedef __bf16 bf16;
typedef __attribute__((ext_vector_type(8))) __bf16 bf16x8;
typedef __attribute__((ext_vector_type(4))) float f32x4;

#define NN 8192
#define F_IN 256
#define F_OUT 128
#define LOG2E 1.44269504088896f
#define ALPHA 0.2f

__device__ __forceinline__ void split8(const float* __restrict__ p,
                                       bf16x8& hi, bf16x8& lo) {
    const float4 u = *(const float4*)p;
    const float4 v = *(const float4*)(p + 4);
    float f[8] = {u.x, u.y, u.z, u.w, v.x, v.y, v.z, v.w};
#pragma unroll
    for (int j = 0; j < 8; ++j) {
        const bf16 h = (bf16)f[j];
        hi[j] = h;
        lo[j] = (bf16)(f[j] - (float)h);
    }
}

// ---------------------------------------------------------------------------
// K1: Wh = h @ W^T (8192x128, K=256) -> transposed bf16 planes. (~3 us)
// ---------------------------------------------------------------------------
__global__ __launch_bounds__(128) void gat_wh(const float* __restrict__ h,
                                              const float* __restrict__ W,
                                              bf16* __restrict__ WhT_hi,
                                              bf16* __restrict__ WhT_lo) {
    const int tid = threadIdx.x;
    const int wv = tid >> 6;
    const int l15 = tid & 15;
    const int g = (tid & 63) >> 4;
    const int rowbase = blockIdx.x * 32 + wv * 16;

    f32x4 acc[8];
    const f32x4 zz = {0.f, 0.f, 0.f, 0.f};
#pragma unroll
    for (int nf = 0; nf < 8; ++nf) acc[nf] = zz;

#pragma unroll
    for (int ks = 0; ks < 8; ++ks) {
        const int k = ks * 32 + g * 8;
        bf16x8 ah, al;
        split8(h + (size_t)(rowbase + l15) * F_IN + k, ah, al);
#pragma unroll
        for (int nf = 0; nf < 8; ++nf) {
            bf16x8 bh, bl;
            split8(W + (size_t)(nf * 16 + l15) * F_IN + k, bh, bl);
            acc[nf] = __builtin_amdgcn_mfma_f32_16x16x32_bf16(ah, bh, acc[nf], 0, 0, 0);
            acc[nf] = __builtin_amdgcn_mfma_f32_16x16x32_bf16(ah, bl, acc[nf], 0, 0, 0);
            acc[nf] = __builtin_amdgcn_mfma_f32_16x16x32_bf16(al, bh, acc[nf], 0, 0, 0);
        }
    }

#pragma unroll
    for (int nf = 0; nf < 8; ++nf)
#pragma unroll
        for (int r = 0; r < 4; ++r) {
            const int row = rowbase + g * 4 + r;
            const int c = nf * 16 + l15;
            const float val = acc[nf][r];
            const bf16 vh = (bf16)val;
            WhT_hi[(size_t)c * NN + row] = vh;
            WhT_lo[(size_t)c * NN + row] = (bf16)(val - (float)vh);
        }
}

// ---------------------------------------------------------------------------
// K2: f1/f2 (fp32, pre-scaled by log2e). (~1 us)
// ---------------------------------------------------------------------------
__global__ __launch_bounds__(64) void gat_f12(const bf16* __restrict__ WhT_hi,
                                              const bf16* __restrict__ WhT_lo,
                                              const float* __restrict__ a,
                                              float* __restrict__ f1L,
                                              float* __restrict__ f2L) {
    const int i = blockIdx.x * 64 + threadIdx.x;
    float s1 = 0.f, s2 = 0.f;
#pragma unroll 8
    for (int c = 0; c < F_OUT; ++c) {
        const float wh = (float)WhT_hi[(size_t)c * NN + i] +
                         (float)WhT_lo[(size_t)c * NN + i];
        s1 += wh * a[c];
        s2 += wh * a[F_OUT + c];
    }
    f1L[i] = s1 * LOG2E;
    f2L[i] = s2 * LOG2E;
}

// ---------------------------------------------------------------------------
// K3: 256 blocks x 512 thr (8 waves = colh(2) x kq(4)).
// Wave: rows [r0,r0+32), cols [64*colh,+64), k in [2048*kq,+2048), 64 steps.
// Per step t: issue B(t+1) (8x16B, L2-hot) + f2(t+1) FIRST, adj(t+2) (4x16B,
// HBM) LAST; compute P(t) in-register in MFMA A-frag layout; 16 MFMAs.
// No barriers in the main loop; epilogue: phased LDS k-reduction over kq.
// ---------------------------------------------------------------------------
__global__ __launch_bounds__(512) void gat_flash(const int* __restrict__ adj,
                                                 const bf16* __restrict__ WhT_hi,
                                                 const bf16* __restrict__ WhT_lo,
                                                 const float* __restrict__ f1L,
                                                 const float* __restrict__ f2L,
                                                 float* __restrict__ out) {
    __shared__ float accL[32][128];
    __shared__ float rsL[32];

    const int tid = threadIdx.x;
    const int wv = tid >> 6;   // 0..7
    const int kq = wv >> 1;    // 0..3 : k-slice of 2048
    const int colh = wv & 1;   // 0..1 : col half of 64
    const int l = tid & 63;
    const int l15 = l & 15;
    const int g = l >> 4;
    const int r0 = blockIdx.x * 32;

    const int kbase = kq * 2048;
    const float f1a = f1L[r0 + l15];
    const float f1b = f1L[r0 + 16 + l15];

    const int* arA = adj + (size_t)(r0 + l15) * NN + kbase + g * 8;
    const int* arB = arA + (size_t)16 * NN;
    const float* f2p = f2L + kbase + g * 8;
    const bf16* bhp = WhT_hi + (size_t)(colh * 64 + l15) * NN + kbase + g * 8;
    const bf16* blp = WhT_lo + (size_t)(colh * 64 + l15) * NN + kbase + g * 8;

    f32x4 accA[4], accB[4];
    const f32x4 zz = {0.f, 0.f, 0.f, 0.f};
#pragma unroll
    for (int ct = 0; ct < 4; ++ct) { accA[ct] = zz; accB[ct] = zz; }
    float rsa = 0.f, rsb = 0.f;

    // ---- prologue (issue order: B(0), f2(0), adj(0), adj(1)) ----
    bf16x8 Bh[4], Bl[4];
#pragma unroll
    for (int ct = 0; ct < 4; ++ct) {
        Bh[ct] = *(const bf16x8*)(bhp + (size_t)ct * 16 * NN);
        Bl[ct] = *(const bf16x8*)(blp + (size_t)ct * 16 * NN);
    }
    float4 fa = *(const float4*)(f2p);
    float4 fb = *(const float4*)(f2p + 4);
    int4 cA0 = *(const int4*)(arA);
    int4 cA1 = *(const int4*)(arA + 4);
    int4 cB0 = *(const int4*)(arB);
    int4 cB1 = *(const int4*)(arB + 4);
    int4 nA0 = *(const int4*)(arA + 32);
    int4 nA1 = *(const int4*)(arA + 36);
    int4 nB0 = *(const int4*)(arB + 32);
    int4 nB1 = *(const int4*)(arB + 36);

    for (int t = 0; t < 64; ++t) {
        const int k1 = ((t + 1 < 64) ? t + 1 : 63) * 32;
        const int k2 = ((t + 2 < 64) ? t + 2 : 63) * 32;

        // ---- phase 1: short-latency prefetch (B(t+1), f2(t+1)) ----
        bf16x8 mBh[4], mBl[4];
#pragma unroll
        for (int ct = 0; ct < 4; ++ct) {
            mBh[ct] = *(const bf16x8*)(bhp + (size_t)ct * 16 * NN + k1);
            mBl[ct] = *(const bf16x8*)(blp + (size_t)ct * 16 * NN + k1);
        }
        float4 mfa = *(const float4*)(f2p + k1);
        float4 mfb = *(const float4*)(f2p + k1 + 4);
        __builtin_amdgcn_sched_barrier(0);

        // ---- phase 2: long-latency prefetch (adj(t+2)), issued LAST ----
        int4 mA0 = *(const int4*)(arA + k2);
        int4 mA1 = *(const int4*)(arA + k2 + 4);
        int4 mB0 = *(const int4*)(arB + k2);
        int4 mB1 = *(const int4*)(arB + k2 + 4);
        __builtin_amdgcn_sched_barrier(0);

        // ---- phase 3: compute with step-t registers ----
        const int aa[8] = {cA0.x, cA0.y, cA0.z, cA0.w, cA1.x, cA1.y, cA1.z, cA1.w};
        const int ab[8] = {cB0.x, cB0.y, cB0.z, cB0.w, cB1.x, cB1.y, cB1.z, cB1.w};
        const float ff[8] = {fa.x, fa.y, fa.z, fa.w, fb.x, fb.y, fb.z, fb.w};

        bf16x8 pa, pb;
#pragma unroll
        for (int j = 0; j < 8; ++j) {
            const float xa = f1a + ff[j];
            const float xb = f1b + ff[j];
            const float ea = __builtin_amdgcn_exp2f(fmaxf(xa, ALPHA * xa));
            const float eb = __builtin_amdgcn_exp2f(fmaxf(xb, ALPHA * xb));
            pa[j] = (bf16)(aa[j] > 0 ? ea : 0.f);
            pb[j] = (bf16)(ab[j] > 0 ? eb : 0.f);
        }
#pragma unroll
        for (int j = 0; j < 8; ++j) {
            rsa += (float)pa[j];
            rsb += (float)pb[j];
        }

#pragma unroll
        for (int ct = 0; ct < 4; ++ct) {
            accA[ct] = __builtin_amdgcn_mfma_f32_16x16x32_bf16(pa, Bh[ct], accA[ct], 0, 0, 0);
            accA[ct] = __builtin_amdgcn_mfma_f32_16x16x32_bf16(pa, Bl[ct], accA[ct], 0, 0, 0);
            accB[ct] = __builtin_amdgcn_mfma_f32_16x16x32_bf16(pb, Bh[ct], accB[ct], 0, 0, 0);
            accB[ct] = __builtin_amdgcn_mfma_f32_16x16x32_bf16(pb, Bl[ct], accB[ct], 0, 0, 0);
        }

        // ---- rotate pipeline registers ----
        cA0 = nA0; cA1 = nA1; cB0 = nB0; cB1 = nB1;
        nA0 = mA0; nA1 = mA1; nB0 = mB0; nB1 = mB1;
#pragma unroll
        for (int ct = 0; ct < 4; ++ct) { Bh[ct] = mBh[ct]; Bl[ct] = mBl[ct]; }
        fa = mfa; fb = mfb;
    }

    // rowsum: combine the 4 g-groups (lanes with equal l15)
    rsa += __shfl_xor(rsa, 16);
    rsa += __shfl_xor(rsa, 32);
    rsb += __shfl_xor(rsb, 16);
    rsb += __shfl_xor(rsb, 32);

    // phased k-split reduction over kq. D layout: row=4*(l>>4)+reg, col=l&15.
    for (int ph = 0; ph < 4; ++ph) {
        if (kq == ph) {
            const int colb = colh * 64 + l15;
#pragma unroll
            for (int ct = 0; ct < 4; ++ct)
#pragma unroll
                for (int r = 0; r < 4; ++r) {
                    const int col = colb + ct * 16;
                    const int rowA = g * 4 + r;
                    const int rowB = 16 + g * 4 + r;
                    if (ph == 0) {
                        accL[rowA][col] = accA[ct][r];
                        accL[rowB][col] = accB[ct][r];
                    } else {
                        accL[rowA][col] += accA[ct][r];
                        accL[rowB][col] += accB[ct][r];
                    }
                }
            if (colh == 0 && l < 16) {
                if (ph == 0) {
                    rsL[l15] = rsa;
                    rsL[16 + l15] = rsb;
                } else {
                    rsL[l15] += rsa;
                    rsL[16 + l15] += rsb;
                }
            }
        }
        __syncthreads();
    }

    // divide + store: 512 thr x 8 floats = 32x128 tile
    const int row = tid >> 4;
    const int col = (tid & 15) * 8;
    const float inv = 1.0f / rsL[row];
    float4 v0 = *(const float4*)&accL[row][col];
    float4 v1 = *(const float4*)&accL[row][col + 4];
    v0.x *= inv; v0.y *= inv; v0.z *= inv; v0.w *= inv;
    v1.x *= inv; v1.y *= inv; v1.z *= inv; v1.w *= inv;
    *(float4*)(out + (size_t)(r0 + row) * F_OUT + col) = v0;
    *(float4*)(out + (size_t)(r0 + row) * F_OUT + col + 4) = v1;
}

// ---------------------------------------------------------------------------
extern "C" void kernel_launch(void* const* d_in, const int* in_sizes, int n_in,
                              void* d_out, int out_size, void* d_ws, size_t ws_size,
                              hipStream_t stream) {
    const float* h = (const float*)d_in[0];  // (8192, 256) fp32
    const int* adj = (const int*)d_in[1];    // (8192, 8192) int32
    const float* W = (const float*)d_in[2];  // (128, 256) fp32
    const float* a = (const float*)d_in[3];  // (1, 256) fp32
    float* out = (float*)d_out;              // (8192, 128) fp32

    char* ws = (char*)d_ws;
    bf16* WhT_hi = (bf16*)ws;                              // 2 MB
    bf16* WhT_lo = (bf16*)(ws + (size_t)2 * 1024 * 1024);  // 2 MB
    float* f1L = (float*)(ws + (size_t)4 * 1024 * 1024);   // 32 KB
    float* f2L = f1L + NN;                                 // 32 KB

    gat_wh<<<256, 128, 0, stream>>>(h, W, WhT_hi, WhT_lo);
    gat_f12<<<NN / 64, 64, 0, stream>>>(WhT_hi, WhT_lo, a, f1L, f2L);
    gat_flash<<<NN / 32, 512, 0, stream>>>(adj, WhT_hi, WhT_lo, f1L, f2L, out);
}